// Round 10
// baseline (521.372 us; speedup 1.0000x reference)
//
#include <hip/hip_runtime.h>

// GRU reward model: swapped-operand MFMA + packed x-stream + gi 2-step pipeline
// + TABLE-DRIVEN gates (round 10).
//   B=1024 seqs, T=1024 steps, Din=36 (obs32+act4+bias), H=64, gates 3H=192.
//   64 blocks x 256 threads (4 waves); block owns 16 sequences.
//   Round-9 postmortem: 24 transcendentals/step at ~16 cyc each = 384 cyc of
//   the 893-cyc step. Replaced by ONE LDS tanh table (4096 entries, +-6.4,
//   nearest-midpoint, built at runtime from __expf -> no hand constants):
//     sigma(x) = 0.5 + 0.5*tanh(x/2)  (0.5 folded into r/z weight rows)
//     tanh(npre) = direct lookup
//   Gate region: 80 cheap VALU + 12 ds_read_b32 instead of 24 trans ops.

#define BB 1024
#define TT 1024
#define DOBS 32
#define DACT 4
#define HH 64

typedef __attribute__((ext_vector_type(8))) short short8;
typedef __attribute__((ext_vector_type(4))) float f32x4;

#define MFMA(A, B, C) __builtin_amdgcn_mfma_f32_16x16x32_bf16((A), (B), (C), 0, 0, 0)

static __device__ __forceinline__ unsigned short f2bf(float f) {
    unsigned u = __float_as_uint(f);
    u += 0x7fffu + ((u >> 16) & 1u);   // RNE
    return (unsigned short)(u >> 16);
}
static __device__ __forceinline__ unsigned cvt_pk(float lo, float hi) {
    unsigned r;
    asm("v_cvt_pk_bf16_f32 %0, %1, %2" : "=v"(r) : "v"(lo), "v"(hi));
    return r;
}

// ---- pre-kernel: xext[(b*TT+t)*40] = bf16 [obs(32), act(4), 1.0, 0,0,0] ----
__global__ __launch_bounds__(256)
void pack_x(const float* __restrict__ obs, const float* __restrict__ act,
            unsigned short* __restrict__ xext)
{
    const size_t r = (size_t)blockIdx.x * 256 + threadIdx.x;   // (b,t) row
    const float* o = obs + r * DOBS;
    unsigned short* d = xext + r * 40;
    short8 v[5];
#pragma unroll
    for (int j = 0; j < 4; ++j) {
        float4 a = ((const float4*)o)[2 * j];
        float4 b = ((const float4*)o)[2 * j + 1];
        short8 t;
        t[0]=f2bf(a.x); t[1]=f2bf(a.y); t[2]=f2bf(a.z); t[3]=f2bf(a.w);
        t[4]=f2bf(b.x); t[5]=f2bf(b.y); t[6]=f2bf(b.z); t[7]=f2bf(b.w);
        v[j] = t;
    }
    {
        float4 a = *(const float4*)(act + r * DACT);
        short8 t;
        t[0]=f2bf(a.x); t[1]=f2bf(a.y); t[2]=f2bf(a.z); t[3]=f2bf(a.w);
        t[4]=(short)0x3f80; t[5]=0; t[6]=0; t[7]=0;   // bias slot k=36
        v[4] = t;
    }
#pragma unroll
    for (int j = 0; j < 5; ++j) ((short8*)d)[j] = v[j];
}

// LOADX: fetch x(t) B-fragments (seq = c). PACKED: no clamp (ws slack rows).
#define LOADX(XO, XA, T)                                                       \
  {                                                                            \
    if (PACKED) {                                                              \
      XO = *(const short8*)(px + (size_t)(T) * 40 + 8 * q);                    \
      XA = (q == 0) ? *(const short8*)(px + (size_t)(T) * 40 + 32) : zero8;    \
    } else {                                                                   \
      const int tc_ = (T) < TT ? (T) : TT - 1;                                 \
      const float* op_ = po + (size_t)tc_ * DOBS + 8 * q;                      \
      float4 a_ = *(const float4*)op_, b_ = *(const float4*)(op_ + 4);         \
      short8 f_;                                                               \
      f_[0]=f2bf(a_.x); f_[1]=f2bf(a_.y); f_[2]=f2bf(a_.z); f_[3]=f2bf(a_.w);  \
      f_[4]=f2bf(b_.x); f_[5]=f2bf(b_.y); f_[6]=f2bf(b_.z); f_[7]=f2bf(b_.w);  \
      XO = f_;                                                                 \
      if (q == 0) {                                                            \
        float4 av_ = *(const float4*)(pa + (size_t)tc_ * DACT);                \
        short8 g_;                                                             \
        g_[0]=f2bf(av_.x); g_[1]=f2bf(av_.y); g_[2]=f2bf(av_.z);               \
        g_[3]=f2bf(av_.w); g_[4]=(short)0x3f80; g_[5]=0; g_[6]=0; g_[7]=0;     \
        XA = g_;                                                               \
      } else XA = zero8;                                                       \
    }                                                                          \
  }

// table lookup index: i = clamp(x*320 + 2048, 0, 4095) (trunc = floor, x>=0)
#define TLOOK(DST, SRC)                                                        \
    { float f_ = fminf(fmaxf(__builtin_fmaf((SRC), 320.0f, 2048.0f), 0.0f),    \
                       4095.0f);                                               \
      DST = ttab[(int)f_]; }

// STEP: PH = literal hbuf phase. CR_/CZ_/CN_ = this parity's gi ring (named).
// r,z weight rows pre-scaled x0.5 (sigma-as-tanh); n rows unscaled.
#define STEP(XO, XA, CR_, CZ_, CN_, PH, T)                                     \
  {                                                                            \
    short8 Ah0 = *(const short8*)((const char*)hbuf[PH] + rdaddr0);            \
    short8 Ah1 = *(const short8*)((const char*)hbuf[PH] + rdaddr1);            \
    f32x4 cr_ = CR_, cz_ = CZ_, cni_ = CN_;      /* gi(T), computed at T-2 */  \
    CR_ = MFMA(AX[0][1], XA, MFMA(AX[0][0], XO, zf));   /* gi(T+2): off-chain */ \
    CZ_ = MFMA(AX[1][1], XA, MFMA(AX[1][0], XO, zf));                          \
    CN_ = MFMA(AX[2][1], XA, MFMA(AX[2][0], XO, zf));                          \
    LOADX(XO, XA, (T) + 4)                       /* refill x ring (t+4) */     \
    f32x4 Cr  = MFMA(AH[0][1], Ah1, MFMA(AH[0][0], Ah0, cr_));                 \
    f32x4 Cz  = MFMA(AH[1][1], Ah1, MFMA(AH[1][0], Ah0, cz_));                 \
    f32x4 Cnh = MFMA(AH[2][1], Ah1, MFMA(AH[2][0], Ah0, bhn4));                \
    f32x4 Crw = zf;                                                            \
    if (w == 3) Crw = MFMA(AR[1], Ah1, MFMA(AR[0], Ah0, zf));                  \
    _Pragma("unroll")                                                          \
    for (int reg = 0; reg < 4; ++reg) {                                        \
      float Tr, Tz, nn;                                                        \
      TLOOK(Tr, Cr[reg])                         /* tanh(rpre/2) */            \
      TLOOK(Tz, Cz[reg])                         /* tanh(zpre/2) */            \
      float d_  = __builtin_fmaf(Tr, Cnh[reg], Cnh[reg]);   /* Cnh*(1+Tr) */   \
      float np  = __builtin_fmaf(0.5f, d_, cni_[reg]);      /* gin + r*ghnb */ \
      TLOOK(nn, np)                              /* n = tanh(npre) */          \
      float a_  = hold[reg] - nn;                                              \
      float b_  = __builtin_fmaf(Tz, a_, a_);    /* (h-n)*(1+Tz) */            \
      hold[reg] = __builtin_fmaf(0.5f, b_, nn);  /* n + z*(h-n) */             \
    }                                                                          \
    unsigned pk0 = cvt_pk(hold[0], hold[1]);                                   \
    unsigned pk1 = cvt_pk(hold[2], hold[3]);                                   \
    *(uint2*)((char*)hbuf[PH ^ 1] + wraddr) = make_uint2(pk0, pk1);            \
    if (w == 3 && q == 0 && (T) > 0)                                           \
      rew[(size_t)(bid * 16 + c) * TT + (T) - 1] = Crw[0] + brr;               \
    asm volatile("s_waitcnt lgkmcnt(0)" ::: "memory");                         \
    __builtin_amdgcn_s_barrier();                                              \
    asm volatile("" ::: "memory");                                             \
  }

template<bool PACKED>
__global__ __launch_bounds__(256, 1)
void gru_fused(const unsigned short* __restrict__ xext,
               const float* __restrict__ obs, const float* __restrict__ act,
               const float* __restrict__ W_ih, const float* __restrict__ b_ih,
               const float* __restrict__ W_hh, const float* __restrict__ b_hh,
               const float* __restrict__ W_r, const float* __restrict__ b_r,
               float* __restrict__ out)
{
    const int tid = threadIdx.x;
    const int w = tid >> 6, l = tid & 63, c = l & 15, q = l >> 4;
    const int bid = blockIdx.x;
    const int u0 = 16 * w + 4 * q;           // first of this lane's 4 units

    __shared__ __align__(16) unsigned short hbuf[2][16 * 64];  // [seq][unit] bf16
    __shared__ float ttab[4096];             // tanh table, +-6.4, delta=1/320

    // ---- build tanh table (runtime; no hand constants). 16 entries/thread ----
#pragma unroll
    for (int i = tid; i < 4096; i += 256) {
        float y = (float)(i - 2048) * (1.0f / 320.0f) + (0.5f / 320.0f); // midpoint
        float e = __expf(2.0f * y);
        ttab[i] = (e - 1.0f) / (e + 1.0f);
    }

    // ---- weight A-fragments: r,z rows x0.5 (sigma-as-tanh); n rows x1 ----
    short8 AX[3][2], AH[3][2];
#pragma unroll
    for (int m = 0; m < 3; ++m) {
        const float sc = (m == 2) ? 1.0f : 0.5f;
        const int j = w + 4 * m;             // tile: w=r, w+4=z, w+8=n
        const int g = 16 * j + c;            // gate row (A-row = c)
        {   // x-weights, k 0..31
            const float* wp = W_ih + (size_t)g * 36 + 8 * q;
            float4 a = *(const float4*)wp, b = *(const float4*)(wp + 4);
            short8 f;
            f[0]=f2bf(a.x*sc); f[1]=f2bf(a.y*sc); f[2]=f2bf(a.z*sc); f[3]=f2bf(a.w*sc);
            f[4]=f2bf(b.x*sc); f[5]=f2bf(b.y*sc); f[6]=f2bf(b.z*sc); f[7]=f2bf(b.w*sc);
            AX[m][0] = f;
        }
        {   // x-weights, k 32..63 (act + bias slot + zeros)
            short8 f;
#pragma unroll
            for (int i = 0; i < 8; ++i) {
                int k = 32 + 8 * q + i;
                float v = 0.f;
                if (k < 36)       v = W_ih[(size_t)g * 36 + k];
                else if (k == 36) v = b_ih[g] + (g < 128 ? b_hh[g] : 0.f);
                f[i] = f2bf(v * sc);
            }
            AX[m][1] = f;
        }
#pragma unroll
        for (int kk = 0; kk < 2; ++kk) {     // h-weights
            const float* wp = W_hh + (size_t)g * HH + 32 * kk + 8 * q;
            float4 a = *(const float4*)wp, b = *(const float4*)(wp + 4);
            short8 f;
            f[0]=f2bf(a.x*sc); f[1]=f2bf(a.y*sc); f[2]=f2bf(a.z*sc); f[3]=f2bf(a.w*sc);
            f[4]=f2bf(b.x*sc); f[5]=f2bf(b.y*sc); f[6]=f2bf(b.z*sc); f[7]=f2bf(b.w*sc);
            AH[m][kk] = f;
        }
    }
    short8 AR[2];                            // reward tile: A-row 0 = W_r (unscaled)
#pragma unroll
    for (int kk = 0; kk < 2; ++kk) {
        short8 f;
#pragma unroll
        for (int i = 0; i < 8; ++i) {
            int k = 32 * kk + 8 * q + i;
            f[i] = (c == 0) ? (short)f2bf(W_r[k]) : (short)0;
        }
        AR[kk] = f;
    }

    f32x4 bhn4;                              // Cnh C-init: b_hh[n-rows] (unscaled)
#pragma unroll
    for (int reg = 0; reg < 4; ++reg) bhn4[reg] = b_hh[128 + u0 + reg];
    const float brr = b_r[0];

    // ---- LDS byte offsets (XOR swizzle on 16B slots within 128B seq-rows) ----
    const int swz = c & 7;
    const int wraddr  = c * 128 + ((((u0 >> 3)) ^ swz) << 4) + (u0 & 7) * 2;
    const int rdaddr0 = c * 128 + ((q ^ swz) << 4);          // units 8q..8q+7
    const int rdaddr1 = c * 128 + (((4 + q) ^ swz) << 4);    // units 32+8q..+7

    // ---- x stream base pointers (lane's seq = c) ----
    const size_t row = (size_t)(bid * 16 + c) * TT;
    const unsigned short* px = xext + row * 40;
    const float* po = obs + row * DOBS;
    const float* pa = act + row * DACT;

    const short8 zero8 = {0, 0, 0, 0, 0, 0, 0, 0};
    const f32x4 zf = {0.f, 0.f, 0.f, 0.f};

    // ---- init: h(-1)=0 in hbuf[0]; prime the x ring + gi pipeline ----
    ((uint2*)hbuf[0])[tid] = make_uint2(0u, 0u);   // 256 x 8B = 2KB = hbuf[0]
    short8 xoA, xaA, xoB, xaB;
    LOADX(xoA, xaA, 0)
    LOADX(xoB, xaB, 1)
    f32x4 cgrA = MFMA(AX[0][1], xaA, MFMA(AX[0][0], xoA, zf));  // gi(0)
    f32x4 cgzA = MFMA(AX[1][1], xaA, MFMA(AX[1][0], xoA, zf));
    f32x4 cgnA = MFMA(AX[2][1], xaA, MFMA(AX[2][0], xoA, zf));
    f32x4 cgrB = MFMA(AX[0][1], xaB, MFMA(AX[0][0], xoB, zf));  // gi(1)
    f32x4 cgzB = MFMA(AX[1][1], xaB, MFMA(AX[1][0], xoB, zf));
    f32x4 cgnB = MFMA(AX[2][1], xaB, MFMA(AX[2][0], xoB, zf));
    LOADX(xoA, xaA, 2)                      // x(2), x(3) into the x ring
    LOADX(xoB, xaB, 3)
    float hold[4] = {0.f, 0.f, 0.f, 0.f};
    asm volatile("s_waitcnt lgkmcnt(0)" ::: "memory");
    __builtin_amdgcn_s_barrier();
    asm volatile("" ::: "memory");

    float* rew = out + (size_t)BB * HH;      // out: [h_final B*H][rewards B*T]

#pragma unroll 1
    for (int t = 0; t < TT; t += 4) {
        STEP(xoA, xaA, cgrA, cgzA, cgnA, 0, t)
        STEP(xoB, xaB, cgrB, cgzB, cgnB, 1, t + 1)
        STEP(xoA, xaA, cgrA, cgzA, cgnA, 0, t + 2)
        STEP(xoB, xaB, cgrB, cgzB, cgnB, 1, t + 3)
    }

    // ---- epilogue: reward(T-1) from h(T-1) (in hbuf[0]); h_final stores ----
    if (w == 3) {
        short8 Ah0 = *(const short8*)((const char*)hbuf[0] + rdaddr0);
        short8 Ah1 = *(const short8*)((const char*)hbuf[0] + rdaddr1);
        f32x4 Crw = MFMA(AR[0], Ah0, zf);
        Crw = MFMA(AR[1], Ah1, Crw);
        if (q == 0)
            rew[(size_t)(bid * 16 + c) * TT + TT - 1] = Crw[0] + brr;
    }
    *(float4*)(out + (size_t)(bid * 16 + c) * HH + u0) =
        make_float4(hold[0], hold[1], hold[2], hold[3]);
}

// ------------------------------------------------------------------- host ---
extern "C" void kernel_launch(void* const* d_in, const int* in_sizes, int n_in,
                              void* d_out, int out_size, void* d_ws, size_t ws_size,
                              hipStream_t stream)
{
    const float* obs    = (const float*)d_in[0];
    const float* action = (const float*)d_in[1];
    const float* W_ih   = (const float*)d_in[2];
    const float* b_ih   = (const float*)d_in[3];
    const float* W_hh   = (const float*)d_in[4];
    const float* b_hh   = (const float*)d_in[5];
    const float* W_r    = (const float*)d_in[6];
    const float* b_r    = (const float*)d_in[7];
    float* out          = (float*)d_out;

    // xext (80 MB) + slack rows so the unclamped t+4 prefetch stays in ws.
    const size_t xext_bytes = ((size_t)BB * TT + 8) * 40 * sizeof(unsigned short);
    if (ws_size >= xext_bytes) {
        unsigned short* xext = (unsigned short*)d_ws;
        pack_x<<<dim3((BB * TT) / 256), dim3(256), 0, stream>>>(obs, action, xext);
        gru_fused<true><<<dim3(BB / 16), dim3(256), 0, stream>>>(
            xext, obs, action, W_ih, b_ih, W_hh, b_hh, W_r, b_r, out);
    } else {
        gru_fused<false><<<dim3(BB / 16), dim3(256), 0, stream>>>(
            nullptr, obs, action, W_ih, b_ih, W_hh, b_hh, W_r, b_r, out);
    }
}

// Round 11
// 437.811 us; speedup vs baseline: 1.1909x; 1.1909x over previous
//
#include <hip/hip_runtime.h>

// GRU reward model: swapped-operand MFMA + packed x-stream + gi 2-step pipeline
// (round-9 structure) + magic-Newton reciprocals + round-robin reward (round 11).
//   B=1024 seqs, T=1024 steps, Din=36 (obs32+act4+bias), H=64, gates 3H=192.
//   64 blocks x 256 threads (4 waves); block owns 16 sequences.
//   A = weight tiles (units in M), B = [x|h] (seqs in N); C = [units x seqs].
//   Round-10 lesson: LDS-table gates put 2 dependent ~120cyc LDS reads ON the
//   chain (15.6M bank conflicts) - reverted. This round cuts trans-pipe ISSUE:
//    - all 12 v_rcp -> magic-constant + 2 Newton steps (5 cheap VALU each,
//      rel err ~2e-5, operands in [1, 2^38] = safely normal)
//    - reward MFMA ownership rotates over waves (w == T&3) so no wave is the
//      per-step straggler on the barrier-synced wall.

#define BB 1024
#define TT 1024
#define DOBS 32
#define DACT 4
#define HH 64

typedef __attribute__((ext_vector_type(8))) short short8;
typedef __attribute__((ext_vector_type(4))) float f32x4;

#define MFMA(A, B, C) __builtin_amdgcn_mfma_f32_16x16x32_bf16((A), (B), (C), 0, 0, 0)

static __device__ __forceinline__ unsigned short f2bf(float f) {
    unsigned u = __float_as_uint(f);
    u += 0x7fffu + ((u >> 16) & 1u);   // RNE
    return (unsigned short)(u >> 16);
}
static __device__ __forceinline__ unsigned cvt_pk(float lo, float hi) {
    unsigned r;
    asm("v_cvt_pk_bf16_f32 %0, %1, %2" : "=v"(r) : "v"(lo), "v"(hi));
    return r;
}
// magic-constant reciprocal + 2 Newton iterations: 5 VALU ops, rel err ~2e-5
static __device__ __forceinline__ float fastrcp(float a) {
    float y = __uint_as_float(0x7EF311C3u - __float_as_uint(a));
    y = y * __builtin_fmaf(-a, y, 2.0f);
    y = y * __builtin_fmaf(-a, y, 2.0f);
    return y;
}

#define L2E 1.442695040888963f

// ---- pre-kernel: xext[(b*TT+t)*40] = bf16 [obs(32), act(4), 1.0, 0,0,0] ----
__global__ __launch_bounds__(256)
void pack_x(const float* __restrict__ obs, const float* __restrict__ act,
            unsigned short* __restrict__ xext)
{
    const size_t r = (size_t)blockIdx.x * 256 + threadIdx.x;   // (b,t) row
    const float* o = obs + r * DOBS;
    unsigned short* d = xext + r * 40;
    short8 v[5];
#pragma unroll
    for (int j = 0; j < 4; ++j) {
        float4 a = ((const float4*)o)[2 * j];
        float4 b = ((const float4*)o)[2 * j + 1];
        short8 t;
        t[0]=f2bf(a.x); t[1]=f2bf(a.y); t[2]=f2bf(a.z); t[3]=f2bf(a.w);
        t[4]=f2bf(b.x); t[5]=f2bf(b.y); t[6]=f2bf(b.z); t[7]=f2bf(b.w);
        v[j] = t;
    }
    {
        float4 a = *(const float4*)(act + r * DACT);
        short8 t;
        t[0]=f2bf(a.x); t[1]=f2bf(a.y); t[2]=f2bf(a.z); t[3]=f2bf(a.w);
        t[4]=(short)0x3f80; t[5]=0; t[6]=0; t[7]=0;   // bias slot k=36
        v[4] = t;
    }
#pragma unroll
    for (int j = 0; j < 5; ++j) ((short8*)d)[j] = v[j];
}

// LOADX: fetch x(t) B-fragments (seq = c). PACKED: no clamp (ws slack rows).
#define LOADX(XO, XA, T)                                                       \
  {                                                                            \
    if (PACKED) {                                                              \
      XO = *(const short8*)(px + (size_t)(T) * 40 + 8 * q);                    \
      XA = (q == 0) ? *(const short8*)(px + (size_t)(T) * 40 + 32) : zero8;    \
    } else {                                                                   \
      const int tc_ = (T) < TT ? (T) : TT - 1;                                 \
      const float* op_ = po + (size_t)tc_ * DOBS + 8 * q;                      \
      float4 a_ = *(const float4*)op_, b_ = *(const float4*)(op_ + 4);         \
      short8 f_;                                                               \
      f_[0]=f2bf(a_.x); f_[1]=f2bf(a_.y); f_[2]=f2bf(a_.z); f_[3]=f2bf(a_.w);  \
      f_[4]=f2bf(b_.x); f_[5]=f2bf(b_.y); f_[6]=f2bf(b_.z); f_[7]=f2bf(b_.w);  \
      XO = f_;                                                                 \
      if (q == 0) {                                                            \
        float4 av_ = *(const float4*)(pa + (size_t)tc_ * DACT);                \
        short8 g_;                                                             \
        g_[0]=f2bf(av_.x); g_[1]=f2bf(av_.y); g_[2]=f2bf(av_.z);               \
        g_[3]=f2bf(av_.w); g_[4]=(short)0x3f80; g_[5]=0; g_[6]=0; g_[7]=0;     \
        XA = g_;                                                               \
      } else XA = zero8;                                                       \
    }                                                                          \
  }

// STEP: PH = literal hbuf phase. CR_/CZ_/CN_ = this parity's gi ring (named).
// Weights pre-scaled: Cr,Cz = -L2E * preact; Cni,Cnh = 2*L2E * preact parts.
// Reward MFMA ownership rotates: wave (T&3) computes reward(T-1).
#define STEP(XO, XA, CR_, CZ_, CN_, PH, T)                                     \
  {                                                                            \
    short8 Ah0 = *(const short8*)((const char*)hbuf[PH] + rdaddr0);            \
    short8 Ah1 = *(const short8*)((const char*)hbuf[PH] + rdaddr1);            \
    f32x4 cr_ = CR_, cz_ = CZ_, cni_ = CN_;      /* gi(T), computed at T-2 */  \
    CR_ = MFMA(AX[0][1], XA, MFMA(AX[0][0], XO, zf));   /* gi(T+2): off-chain */ \
    CZ_ = MFMA(AX[1][1], XA, MFMA(AX[1][0], XO, zf));                          \
    CN_ = MFMA(AX[2][1], XA, MFMA(AX[2][0], XO, zf));                          \
    LOADX(XO, XA, (T) + 4)                       /* refill x ring (t+4) */     \
    f32x4 Cr  = MFMA(AH[0][1], Ah1, MFMA(AH[0][0], Ah0, cr_));                 \
    f32x4 Cz  = MFMA(AH[1][1], Ah1, MFMA(AH[1][0], Ah0, cz_));                 \
    f32x4 Cnh = MFMA(AH[2][1], Ah1, MFMA(AH[2][0], Ah0, bhn4));                \
    f32x4 Crw = zf;                                                            \
    if (w == ((T) & 3)) Crw = MFMA(AR[1], Ah1, MFMA(AR[0], Ah0, zf));          \
    _Pragma("unroll")                                                          \
    for (int reg = 0; reg < 4; ++reg) {                                        \
      float rr   = fastrcp(1.0f + __builtin_amdgcn_exp2f(Cr[reg]));            \
      float zz   = fastrcp(1.0f + __builtin_amdgcn_exp2f(Cz[reg]));            \
      float E    = __builtin_amdgcn_exp2f(__builtin_fmaf(rr, Cnh[reg], cni_[reg])); \
      float nn   = __builtin_fmaf(-2.0f, fastrcp(E + 1.0f), 1.0f);             \
      hold[reg]  = __builtin_fmaf(zz, hold[reg] - nn, nn);                     \
    }                                                                          \
    unsigned pk0 = cvt_pk(hold[0], hold[1]);                                   \
    unsigned pk1 = cvt_pk(hold[2], hold[3]);                                   \
    *(uint2*)((char*)hbuf[PH ^ 1] + wraddr) = make_uint2(pk0, pk1);            \
    if (w == ((T) & 3) && q == 0 && (T) > 0)                                   \
      rew[(size_t)(bid * 16 + c) * TT + (T) - 1] = Crw[0] + brr;               \
    asm volatile("s_waitcnt lgkmcnt(0)" ::: "memory");                         \
    __builtin_amdgcn_s_barrier();                                              \
    asm volatile("" ::: "memory");                                             \
  }

template<bool PACKED>
__global__ __launch_bounds__(256, 1)
void gru_fused(const unsigned short* __restrict__ xext,
               const float* __restrict__ obs, const float* __restrict__ act,
               const float* __restrict__ W_ih, const float* __restrict__ b_ih,
               const float* __restrict__ W_hh, const float* __restrict__ b_hh,
               const float* __restrict__ W_r, const float* __restrict__ b_r,
               float* __restrict__ out)
{
    const int tid = threadIdx.x;
    const int w = tid >> 6, l = tid & 63, c = l & 15, q = l >> 4;
    const int bid = blockIdx.x;
    const int u0 = 16 * w + 4 * q;           // first of this lane's 4 units

    __shared__ __align__(16) unsigned short hbuf[2][16 * 64];  // [seq][unit] bf16

    // ---- weight A-fragments, PRE-SCALED for the gate exp2s ----
    //   m=0 (r), m=1 (z): rows * -L2E;  m=2 (n): rows * +2*L2E.
    short8 AX[3][2], AH[3][2];
#pragma unroll
    for (int m = 0; m < 3; ++m) {
        const float sc = (m == 2) ? (2.0f * L2E) : (-L2E);
        const int j = w + 4 * m;             // tile: w=r, w+4=z, w+8=n
        const int g = 16 * j + c;            // gate row (A-row = c)
        {   // x-weights, k 0..31
            const float* wp = W_ih + (size_t)g * 36 + 8 * q;
            float4 a = *(const float4*)wp, b = *(const float4*)(wp + 4);
            short8 f;
            f[0]=f2bf(a.x*sc); f[1]=f2bf(a.y*sc); f[2]=f2bf(a.z*sc); f[3]=f2bf(a.w*sc);
            f[4]=f2bf(b.x*sc); f[5]=f2bf(b.y*sc); f[6]=f2bf(b.z*sc); f[7]=f2bf(b.w*sc);
            AX[m][0] = f;
        }
        {   // x-weights, k 32..63 (act + bias slot + zeros)
            short8 f;
#pragma unroll
            for (int i = 0; i < 8; ++i) {
                int k = 32 + 8 * q + i;
                float v = 0.f;
                if (k < 36)       v = W_ih[(size_t)g * 36 + k];
                else if (k == 36) v = b_ih[g] + (g < 128 ? b_hh[g] : 0.f);
                f[i] = f2bf(v * sc);
            }
            AX[m][1] = f;
        }
#pragma unroll
        for (int kk = 0; kk < 2; ++kk) {     // h-weights
            const float* wp = W_hh + (size_t)g * HH + 32 * kk + 8 * q;
            float4 a = *(const float4*)wp, b = *(const float4*)(wp + 4);
            short8 f;
            f[0]=f2bf(a.x*sc); f[1]=f2bf(a.y*sc); f[2]=f2bf(a.z*sc); f[3]=f2bf(a.w*sc);
            f[4]=f2bf(b.x*sc); f[5]=f2bf(b.y*sc); f[6]=f2bf(b.z*sc); f[7]=f2bf(b.w*sc);
            AH[m][kk] = f;
        }
    }
    short8 AR[2];                            // reward tile: A-row 0 = W_r (unscaled)
#pragma unroll
    for (int kk = 0; kk < 2; ++kk) {
        short8 f;
#pragma unroll
        for (int i = 0; i < 8; ++i) {
            int k = 32 * kk + 8 * q + i;
            f[i] = (c == 0) ? (short)f2bf(W_r[k]) : (short)0;
        }
        AR[kk] = f;
    }

    f32x4 bhn4;                              // Cnh C-init: 2*L2E * b_hh[n-rows]
#pragma unroll
    for (int reg = 0; reg < 4; ++reg) bhn4[reg] = b_hh[128 + u0 + reg] * (2.0f * L2E);
    const float brr = b_r[0];

    // ---- LDS byte offsets (XOR swizzle on 16B slots within 128B seq-rows) ----
    const int swz = c & 7;
    const int wraddr  = c * 128 + ((((u0 >> 3)) ^ swz) << 4) + (u0 & 7) * 2;
    const int rdaddr0 = c * 128 + ((q ^ swz) << 4);          // units 8q..8q+7
    const int rdaddr1 = c * 128 + (((4 + q) ^ swz) << 4);    // units 32+8q..+7

    // ---- x stream base pointers (lane's seq = c) ----
    const size_t row = (size_t)(bid * 16 + c) * TT;
    const unsigned short* px = xext + row * 40;
    const float* po = obs + row * DOBS;
    const float* pa = act + row * DACT;

    const short8 zero8 = {0, 0, 0, 0, 0, 0, 0, 0};
    const f32x4 zf = {0.f, 0.f, 0.f, 0.f};

    // ---- init: h(-1)=0 in hbuf[0]; prime the x ring + gi pipeline ----
    ((uint2*)hbuf[0])[tid] = make_uint2(0u, 0u);   // 256 x 8B = 2KB = hbuf[0]
    short8 xoA, xaA, xoB, xaB;
    LOADX(xoA, xaA, 0)
    LOADX(xoB, xaB, 1)
    f32x4 cgrA = MFMA(AX[0][1], xaA, MFMA(AX[0][0], xoA, zf));  // gi(0)
    f32x4 cgzA = MFMA(AX[1][1], xaA, MFMA(AX[1][0], xoA, zf));
    f32x4 cgnA = MFMA(AX[2][1], xaA, MFMA(AX[2][0], xoA, zf));
    f32x4 cgrB = MFMA(AX[0][1], xaB, MFMA(AX[0][0], xoB, zf));  // gi(1)
    f32x4 cgzB = MFMA(AX[1][1], xaB, MFMA(AX[1][0], xoB, zf));
    f32x4 cgnB = MFMA(AX[2][1], xaB, MFMA(AX[2][0], xoB, zf));
    LOADX(xoA, xaA, 2)                      // x(2), x(3) into the x ring
    LOADX(xoB, xaB, 3)
    float hold[4] = {0.f, 0.f, 0.f, 0.f};
    asm volatile("s_waitcnt lgkmcnt(0)" ::: "memory");
    __builtin_amdgcn_s_barrier();
    asm volatile("" ::: "memory");

    float* rew = out + (size_t)BB * HH;      // out: [h_final B*H][rewards B*T]

#pragma unroll 1
    for (int t = 0; t < TT; t += 4) {
        STEP(xoA, xaA, cgrA, cgzA, cgnA, 0, t)
        STEP(xoB, xaB, cgrB, cgzB, cgnB, 1, t + 1)
        STEP(xoA, xaA, cgrA, cgzA, cgnA, 0, t + 2)
        STEP(xoB, xaB, cgrB, cgzB, cgnB, 1, t + 3)
    }

    // ---- epilogue: reward(T-1) from h(T-1) (in hbuf[0]); h_final stores ----
    if (w == 3) {
        short8 Ah0 = *(const short8*)((const char*)hbuf[0] + rdaddr0);
        short8 Ah1 = *(const short8*)((const char*)hbuf[0] + rdaddr1);
        f32x4 Crw = MFMA(AR[0], Ah0, zf);
        Crw = MFMA(AR[1], Ah1, Crw);
        if (q == 0)
            rew[(size_t)(bid * 16 + c) * TT + TT - 1] = Crw[0] + brr;
    }
    *(float4*)(out + (size_t)(bid * 16 + c) * HH + u0) =
        make_float4(hold[0], hold[1], hold[2], hold[3]);
}

// ------------------------------------------------------------------- host ---
extern "C" void kernel_launch(void* const* d_in, const int* in_sizes, int n_in,
                              void* d_out, int out_size, void* d_ws, size_t ws_size,
                              hipStream_t stream)
{
    const float* obs    = (const float*)d_in[0];
    const float* action = (const float*)d_in[1];
    const float* W_ih   = (const float*)d_in[2];
    const float* b_ih   = (const float*)d_in[3];
    const float* W_hh   = (const float*)d_in[4];
    const float* b_hh   = (const float*)d_in[5];
    const float* W_r    = (const float*)d_in[6];
    const float* b_r    = (const float*)d_in[7];
    float* out          = (float*)d_out;

    // xext (80 MB) + slack rows so the unclamped t+4 prefetch stays in ws.
    const size_t xext_bytes = ((size_t)BB * TT + 8) * 40 * sizeof(unsigned short);
    if (ws_size >= xext_bytes) {
        unsigned short* xext = (unsigned short*)d_ws;
        pack_x<<<dim3((BB * TT) / 256), dim3(256), 0, stream>>>(obs, action, xext);
        gru_fused<true><<<dim3(BB / 16), dim3(256), 0, stream>>>(
            xext, obs, action, W_ih, b_ih, W_hh, b_hh, W_r, b_r, out);
    } else {
        gru_fused<false><<<dim3(BB / 16), dim3(256), 0, stream>>>(
            nullptr, obs, action, W_ih, b_ih, W_hh, b_hh, W_r, b_r, out);
    }
}

// Round 14
// 399.761 us; speedup vs baseline: 1.3042x; 1.0952x over previous
//
#include <hip/hip_runtime.h>

// GRU reward model, round 13b: 8-wave role-alternating schedule + fp32 h carry.
//   (round 13 with the float[4]/f32x4 compile bug fixed: hold is f32x4)
//   B=1024 seqs, T=1024 steps, Din=36 (obs32+act4+bias), H=64, gates 3H=192.
//   64 blocks x 512 threads (8 waves = 2/SIMD); block owns 16 sequences.
//   Set A (waves 0-3) owns EVEN steps, set B (waves 4-7) ODD steps.
//   h carried in LDS in TWO forms, double-buffered by step parity:
//     hbuf[2] : bf16 [seq][unit] for the MFMA B-fragments (cross-lane)
//     hf32[2] : fp32 [seq][unit]; each lane round-trips its OWN 4 units
//               (ds_read_b128/ds_write_b128) -> lossless carry, math is
//               bit-identical to round 9 (absmax must be 0.0078125).
//   Per half-iteration: active set runs HEAVY (ds_read h -> h-MFMAs -> gates ->
//   ds_write), idle set runs LIGHT (gi MFMAs + x prefetch, no LDS) -> each
//   SIMD pairs one A-wave with one B-wave and fills the other's stalls.

#define BB 1024
#define TT 1024
#define DOBS 32
#define DACT 4
#define HH 64

typedef __attribute__((ext_vector_type(8))) short short8;
typedef __attribute__((ext_vector_type(4))) float f32x4;

#define MFMA(A, B, C) __builtin_amdgcn_mfma_f32_16x16x32_bf16((A), (B), (C), 0, 0, 0)

static __device__ __forceinline__ unsigned short f2bf(float f) {
    unsigned u = __float_as_uint(f);
    u += 0x7fffu + ((u >> 16) & 1u);   // RNE
    return (unsigned short)(u >> 16);
}
static __device__ __forceinline__ float frcp(float x) { return __builtin_amdgcn_rcpf(x); }
static __device__ __forceinline__ unsigned cvt_pk(float lo, float hi) {
    unsigned r;
    asm("v_cvt_pk_bf16_f32 %0, %1, %2" : "=v"(r) : "v"(lo), "v"(hi));
    return r;
}

#define L2E 1.442695040888963f

// ---- pre-kernel: xext[(b*TT+t)*40] = bf16 [obs(32), act(4), 1.0, 0,0,0] ----
__global__ __launch_bounds__(256)
void pack_x(const float* __restrict__ obs, const float* __restrict__ act,
            unsigned short* __restrict__ xext)
{
    const size_t r = (size_t)blockIdx.x * 256 + threadIdx.x;   // (b,t) row
    const float* o = obs + r * DOBS;
    unsigned short* d = xext + r * 40;
    short8 v[5];
#pragma unroll
    for (int j = 0; j < 4; ++j) {
        float4 a = ((const float4*)o)[2 * j];
        float4 b = ((const float4*)o)[2 * j + 1];
        short8 t;
        t[0]=f2bf(a.x); t[1]=f2bf(a.y); t[2]=f2bf(a.z); t[3]=f2bf(a.w);
        t[4]=f2bf(b.x); t[5]=f2bf(b.y); t[6]=f2bf(b.z); t[7]=f2bf(b.w);
        v[j] = t;
    }
    {
        float4 a = *(const float4*)(act + r * DACT);
        short8 t;
        t[0]=f2bf(a.x); t[1]=f2bf(a.y); t[2]=f2bf(a.z); t[3]=f2bf(a.w);
        t[4]=(short)0x3f80; t[5]=0; t[6]=0; t[7]=0;   // bias slot k=36
        v[4] = t;
    }
#pragma unroll
    for (int j = 0; j < 5; ++j) ((short8*)d)[j] = v[j];
}

// LOADX: fetch x(t) B-fragments (seq = c). PACKED: no clamp (ws slack rows).
#define LOADX(XO, XA, T)                                                       \
  {                                                                            \
    if (PACKED) {                                                              \
      XO = *(const short8*)(px + (size_t)(T) * 40 + 8 * q);                    \
      XA = (q == 0) ? *(const short8*)(px + (size_t)(T) * 40 + 32) : zero8;    \
    } else {                                                                   \
      const int tc_ = (T) < TT ? (T) : TT - 1;                                 \
      const float* op_ = po + (size_t)tc_ * DOBS + 8 * q;                      \
      float4 a_ = *(const float4*)op_, b_ = *(const float4*)(op_ + 4);         \
      short8 f_;                                                               \
      f_[0]=f2bf(a_.x); f_[1]=f2bf(a_.y); f_[2]=f2bf(a_.z); f_[3]=f2bf(a_.w);  \
      f_[4]=f2bf(b_.x); f_[5]=f2bf(b_.y); f_[6]=f2bf(b_.z); f_[7]=f2bf(b_.w);  \
      XO = f_;                                                                 \
      if (q == 0) {                                                            \
        float4 av_ = *(const float4*)(pa + (size_t)tc_ * DACT);                \
        short8 g_;                                                             \
        g_[0]=f2bf(av_.x); g_[1]=f2bf(av_.y); g_[2]=f2bf(av_.z);               \
        g_[3]=f2bf(av_.w); g_[4]=(short)0x3f80; g_[5]=0; g_[6]=0; g_[7]=0;     \
        XA = g_;                                                               \
      } else XA = zero8;                                                       \
    }                                                                          \
  }

// HEAVY: h-dependent step work. PH literal. h(T-1) fp32 via hf32[PH] (own 4
// units, lossless); bf16 hbuf feeds the MFMA fragments.
// Weights pre-scaled: Cr,Cz = -L2E*preact; Cnh,cgn = 2*L2E*preact parts.
#define HEAVY(PH, T, IT)                                                       \
  {                                                                            \
    short8 Ah0 = *(const short8*)((const char*)hbuf[PH] + rdaddr0);            \
    short8 Ah1 = *(const short8*)((const char*)hbuf[PH] + rdaddr1);            \
    f32x4 hp = *(const f32x4*)((const char*)hf32[PH] + f32addr);               \
    f32x4 Cr  = MFMA(AH[0][1], Ah1, MFMA(AH[0][0], Ah0, cgr));                 \
    f32x4 Cz  = MFMA(AH[1][1], Ah1, MFMA(AH[1][0], Ah0, cgz));                 \
    f32x4 Cnh = MFMA(AH[2][1], Ah1, MFMA(AH[2][0], Ah0, bhn4));                \
    f32x4 Crw = zf;                                                            \
    const bool dorw_ = (w == ((IT) & 3));                                      \
    if (dorw_) Crw = MFMA(AR[1], Ah1, MFMA(AR[0], Ah0, zf));                   \
    _Pragma("unroll")                                                          \
    for (int reg = 0; reg < 4; ++reg) {                                        \
      float rr   = frcp(1.0f + __builtin_amdgcn_exp2f(Cr[reg]));               \
      float zz   = frcp(1.0f + __builtin_amdgcn_exp2f(Cz[reg]));               \
      float E    = __builtin_amdgcn_exp2f(__builtin_fmaf(rr, Cnh[reg], cgn[reg])); \
      float nn   = __builtin_fmaf(-2.0f, frcp(E + 1.0f), 1.0f);                \
      hold[reg]  = __builtin_fmaf(zz, hp[reg] - nn, nn);                       \
    }                                                                          \
    unsigned pk0 = cvt_pk(hold[0], hold[1]);                                   \
    unsigned pk1 = cvt_pk(hold[2], hold[3]);                                   \
    *(uint2*)((char*)hbuf[PH ^ 1] + wraddr) = make_uint2(pk0, pk1);            \
    *(f32x4*)((char*)hf32[PH ^ 1] + f32addr) = hold;                           \
    if (dorw_ && q == 0 && (T) > 0)                                            \
      rew[(size_t)(bid * 16 + c) * TT + (T) - 1] = Crw[0] + brr;               \
    asm volatile("s_waitcnt lgkmcnt(0)" ::: "memory");                         \
  }

// LIGHT: gi(T2) from the x ring, then refill ring with x(T2+2). No LDS ops.
#define LIGHT(T2)                                                              \
  {                                                                            \
    cgr = MFMA(AX[0][1], xa, MFMA(AX[0][0], xo, zf));                          \
    cgz = MFMA(AX[1][1], xa, MFMA(AX[1][0], xo, zf));                          \
    cgn = MFMA(AX[2][1], xa, MFMA(AX[2][0], xo, zf));                          \
    LOADX(xo, xa, (T2) + 2)                                                    \
  }

template<bool PACKED>
__global__ __launch_bounds__(512, 1)
void gru_fused(const unsigned short* __restrict__ xext,
               const float* __restrict__ obs, const float* __restrict__ act,
               const float* __restrict__ W_ih, const float* __restrict__ b_ih,
               const float* __restrict__ W_hh, const float* __restrict__ b_hh,
               const float* __restrict__ W_r, const float* __restrict__ b_r,
               float* __restrict__ out)
{
    const int tid = threadIdx.x;
    const int set = tid >> 8;                // 0: even steps, 1: odd steps
    const int w = (tid >> 6) & 3;            // wave-in-set
    const int l = tid & 63, c = l & 15, q = l >> 4;
    const int bid = blockIdx.x;
    const int u0 = 16 * w + 4 * q;           // first of this lane's 4 units

    __shared__ __align__(16) unsigned short hbuf[2][16 * 64];  // bf16 [seq][unit]
    __shared__ __align__(16) float          hf32[2][16 * 64];  // fp32 [seq][unit]

    // ---- weight A-fragments, PRE-SCALED for the gate exp2s ----
    //   m=0 (r), m=1 (z): rows * -L2E;  m=2 (n): rows * +2*L2E.
    short8 AX[3][2], AH[3][2];
#pragma unroll
    for (int m = 0; m < 3; ++m) {
        const float sc = (m == 2) ? (2.0f * L2E) : (-L2E);
        const int j = w + 4 * m;             // tile: w=r, w+4=z, w+8=n
        const int g = 16 * j + c;            // gate row (A-row = c)
        {   // x-weights, k 0..31
            const float* wp = W_ih + (size_t)g * 36 + 8 * q;
            float4 a = *(const float4*)wp, b = *(const float4*)(wp + 4);
            short8 f;
            f[0]=f2bf(a.x*sc); f[1]=f2bf(a.y*sc); f[2]=f2bf(a.z*sc); f[3]=f2bf(a.w*sc);
            f[4]=f2bf(b.x*sc); f[5]=f2bf(b.y*sc); f[6]=f2bf(b.z*sc); f[7]=f2bf(b.w*sc);
            AX[m][0] = f;
        }
        {   // x-weights, k 32..63 (act + bias slot + zeros)
            short8 f;
#pragma unroll
            for (int i = 0; i < 8; ++i) {
                int k = 32 + 8 * q + i;
                float v = 0.f;
                if (k < 36)       v = W_ih[(size_t)g * 36 + k];
                else if (k == 36) v = b_ih[g] + (g < 128 ? b_hh[g] : 0.f);
                f[i] = f2bf(v * sc);
            }
            AX[m][1] = f;
        }
#pragma unroll
        for (int kk = 0; kk < 2; ++kk) {     // h-weights
            const float* wp = W_hh + (size_t)g * HH + 32 * kk + 8 * q;
            float4 a = *(const float4*)wp, b = *(const float4*)(wp + 4);
            short8 f;
            f[0]=f2bf(a.x*sc); f[1]=f2bf(a.y*sc); f[2]=f2bf(a.z*sc); f[3]=f2bf(a.w*sc);
            f[4]=f2bf(b.x*sc); f[5]=f2bf(b.y*sc); f[6]=f2bf(b.z*sc); f[7]=f2bf(b.w*sc);
            AH[m][kk] = f;
        }
    }
    short8 AR[2];                            // reward tile: A-row 0 = W_r (unscaled)
#pragma unroll
    for (int kk = 0; kk < 2; ++kk) {
        short8 f;
#pragma unroll
        for (int i = 0; i < 8; ++i) {
            int k = 32 * kk + 8 * q + i;
            f[i] = (c == 0) ? (short)f2bf(W_r[k]) : (short)0;
        }
        AR[kk] = f;
    }

    f32x4 bhn4;                              // Cnh C-init: 2*L2E * b_hh[n-rows]
#pragma unroll
    for (int reg = 0; reg < 4; ++reg) bhn4[reg] = b_hh[128 + u0 + reg] * (2.0f * L2E);
    const float brr = b_r[0];

    // ---- LDS byte offsets ----
    // hbuf: XOR swizzle on 16B slots within 128B seq-rows (proven benign).
    const int swz = c & 7;
    const int wraddr  = c * 128 + ((((u0 >> 3)) ^ swz) << 4) + (u0 & 7) * 2;
    const int rdaddr0 = c * 128 + ((q ^ swz) << 4);          // units 8q..8q+7
    const int rdaddr1 = c * 128 + (((4 + q) ^ swz) << 4);    // units 32+8q..+7
    // hf32: 256B seq-rows of 16 float4-slots; lane's slot (4w+q), XOR-swizzled.
    const int f32addr = c * 256 + (((4 * w + q) ^ swz) << 4);

    // ---- x stream base pointers (lane's seq = c) ----
    const size_t row = (size_t)(bid * 16 + c) * TT;
    const unsigned short* px = xext + row * 40;
    const float* po = obs + row * DOBS;
    const float* pa = act + row * DACT;

    const short8 zero8 = {0, 0, 0, 0, 0, 0, 0, 0};
    const f32x4 zf = {0.f, 0.f, 0.f, 0.f};

    // ---- init: zero hbuf (4KB) + hf32 (8KB); prime per-set x/gi state ----
    ((uint2*)hbuf)[tid] = make_uint2(0u, 0u);          // 512 x 8B = 4KB
    ((f32x4*)hf32)[tid] = zf;                          // 512 x 16B = 8KB
    short8 xo, xa;
    f32x4 cgr = zf, cgz = zf, cgn = zf;
    if (set == 0) {
        LOADX(xo, xa, 0)                    // x(0)
        cgr = MFMA(AX[0][1], xa, MFMA(AX[0][0], xo, zf));   // gi(0)
        cgz = MFMA(AX[1][1], xa, MFMA(AX[1][0], xo, zf));
        cgn = MFMA(AX[2][1], xa, MFMA(AX[2][0], xo, zf));
        LOADX(xo, xa, 2)                    // x(2) -> ring
    } else {
        LOADX(xo, xa, 1)                    // x(1) -> ring (gi(1) built in light)
    }
    f32x4 hold = zf;
    asm volatile("s_waitcnt lgkmcnt(0)" ::: "memory");
    __builtin_amdgcn_s_barrier();
    asm volatile("" ::: "memory");

    float* rew = out + (size_t)BB * HH;      // out: [h_final B*H][rewards B*T]

#pragma unroll 1
    for (int it = 0; it < TT / 2; ++it) {
        const int Ta = 2 * it, Tb = 2 * it + 1;
        // half 1: A heavy (step Ta), B light (gi for Tb)
        if (set == 0) { HEAVY(0, Ta, it) } else { LIGHT(Tb) }
        __builtin_amdgcn_s_barrier();
        asm volatile("" ::: "memory");
        // half 2: B heavy (step Tb), A light (gi for Ta+2)
        if (set == 1) { HEAVY(1, Tb, it) } else { LIGHT(Ta + 2) }
        __builtin_amdgcn_s_barrier();
        asm volatile("" ::: "memory");
    }

    // ---- epilogue: h(T-1) is in hbuf[0]/hold of set B (T-1 = 1023 odd) ----
    if (set == 1) {
        if (w == 3) {
            short8 Ah0 = *(const short8*)((const char*)hbuf[0] + rdaddr0);
            short8 Ah1 = *(const short8*)((const char*)hbuf[0] + rdaddr1);
            f32x4 Crw = MFMA(AR[0], Ah0, zf);
            Crw = MFMA(AR[1], Ah1, Crw);
            if (q == 0)
                rew[(size_t)(bid * 16 + c) * TT + TT - 1] = Crw[0] + brr;
        }
        *(float4*)(out + (size_t)(bid * 16 + c) * HH + u0) =
            make_float4(hold[0], hold[1], hold[2], hold[3]);
    }
}

// ------------------------------------------------------------------- host ---
extern "C" void kernel_launch(void* const* d_in, const int* in_sizes, int n_in,
                              void* d_out, int out_size, void* d_ws, size_t ws_size,
                              hipStream_t stream)
{
    const float* obs    = (const float*)d_in[0];
    const float* action = (const float*)d_in[1];
    const float* W_ih   = (const float*)d_in[2];
    const float* b_ih   = (const float*)d_in[3];
    const float* W_hh   = (const float*)d_in[4];
    const float* b_hh   = (const float*)d_in[5];
    const float* W_r    = (const float*)d_in[6];
    const float* b_r    = (const float*)d_in[7];
    float* out          = (float*)d_out;

    // xext (80 MB) + slack rows so the unclamped t+4 prefetch stays in ws.
    const size_t xext_bytes = ((size_t)BB * TT + 8) * 40 * sizeof(unsigned short);
    if (ws_size >= xext_bytes) {
        unsigned short* xext = (unsigned short*)d_ws;
        pack_x<<<dim3((BB * TT) / 256), dim3(256), 0, stream>>>(obs, action, xext);
        gru_fused<true><<<dim3(BB / 16), dim3(512), 0, stream>>>(
            xext, obs, action, W_ih, b_ih, W_hh, b_hh, W_r, b_r, out);
    } else {
        gru_fused<false><<<dim3(BB / 16), dim3(512), 0, stream>>>(
            nullptr, obs, action, W_ih, b_ih, W_hh, b_hh, W_r, b_r, out);
    }
}

// Round 15
// 398.651 us; speedup vs baseline: 1.3078x; 1.0028x over previous
//
#include <hip/hip_runtime.h>

// GRU reward model, round 15: round-14 structure + s_setprio on the HEAVY wave.
//   B=1024 seqs, T=1024 steps, Din=36 (obs32+act4+bias), H=64, gates 3H=192.
//   64 blocks x 512 threads (8 waves = 2/SIMD); block owns 16 sequences.
//   Set A (waves 0-3) owns EVEN steps, set B (waves 4-7) ODD steps.
//   h carried in LDS: hbuf[2] bf16 (MFMA fragments) + hf32[2] fp32 (lossless
//   own-lane carry). One s_barrier per step; vmcnt never drains.
//   NEW (T5): HEAVY runs at wave priority 1, LIGHT at 0 -> the partner wave's
//   12-MFMA LIGHT burst can no longer queue ahead of HEAVY's chain-critical
//   ops on the shared SIMD issue port (m218b/m191 mechanism: role-split waves).

#define BB 1024
#define TT 1024
#define DOBS 32
#define DACT 4
#define HH 64

typedef __attribute__((ext_vector_type(8))) short short8;
typedef __attribute__((ext_vector_type(4))) float f32x4;

#define MFMA(A, B, C) __builtin_amdgcn_mfma_f32_16x16x32_bf16((A), (B), (C), 0, 0, 0)

static __device__ __forceinline__ unsigned short f2bf(float f) {
    unsigned u = __float_as_uint(f);
    u += 0x7fffu + ((u >> 16) & 1u);   // RNE
    return (unsigned short)(u >> 16);
}
static __device__ __forceinline__ float frcp(float x) { return __builtin_amdgcn_rcpf(x); }
static __device__ __forceinline__ unsigned cvt_pk(float lo, float hi) {
    unsigned r;
    asm("v_cvt_pk_bf16_f32 %0, %1, %2" : "=v"(r) : "v"(lo), "v"(hi));
    return r;
}

#define L2E 1.442695040888963f

// ---- pre-kernel: xext[(b*TT+t)*40] = bf16 [obs(32), act(4), 1.0, 0,0,0] ----
__global__ __launch_bounds__(256)
void pack_x(const float* __restrict__ obs, const float* __restrict__ act,
            unsigned short* __restrict__ xext)
{
    const size_t r = (size_t)blockIdx.x * 256 + threadIdx.x;   // (b,t) row
    const float* o = obs + r * DOBS;
    unsigned short* d = xext + r * 40;
    short8 v[5];
#pragma unroll
    for (int j = 0; j < 4; ++j) {
        float4 a = ((const float4*)o)[2 * j];
        float4 b = ((const float4*)o)[2 * j + 1];
        short8 t;
        t[0]=f2bf(a.x); t[1]=f2bf(a.y); t[2]=f2bf(a.z); t[3]=f2bf(a.w);
        t[4]=f2bf(b.x); t[5]=f2bf(b.y); t[6]=f2bf(b.z); t[7]=f2bf(b.w);
        v[j] = t;
    }
    {
        float4 a = *(const float4*)(act + r * DACT);
        short8 t;
        t[0]=f2bf(a.x); t[1]=f2bf(a.y); t[2]=f2bf(a.z); t[3]=f2bf(a.w);
        t[4]=(short)0x3f80; t[5]=0; t[6]=0; t[7]=0;   // bias slot k=36
        v[4] = t;
    }
#pragma unroll
    for (int j = 0; j < 5; ++j) ((short8*)d)[j] = v[j];
}

// LOADX: fetch x(t) B-fragments (seq = c). PACKED: no clamp (ws slack rows).
#define LOADX(XO, XA, T)                                                       \
  {                                                                            \
    if (PACKED) {                                                              \
      XO = *(const short8*)(px + (size_t)(T) * 40 + 8 * q);                    \
      XA = (q == 0) ? *(const short8*)(px + (size_t)(T) * 40 + 32) : zero8;    \
    } else {                                                                   \
      const int tc_ = (T) < TT ? (T) : TT - 1;                                 \
      const float* op_ = po + (size_t)tc_ * DOBS + 8 * q;                      \
      float4 a_ = *(const float4*)op_, b_ = *(const float4*)(op_ + 4);         \
      short8 f_;                                                               \
      f_[0]=f2bf(a_.x); f_[1]=f2bf(a_.y); f_[2]=f2bf(a_.z); f_[3]=f2bf(a_.w);  \
      f_[4]=f2bf(b_.x); f_[5]=f2bf(b_.y); f_[6]=f2bf(b_.z); f_[7]=f2bf(b_.w);  \
      XO = f_;                                                                 \
      if (q == 0) {                                                            \
        float4 av_ = *(const float4*)(pa + (size_t)tc_ * DACT);                \
        short8 g_;                                                             \
        g_[0]=f2bf(av_.x); g_[1]=f2bf(av_.y); g_[2]=f2bf(av_.z);               \
        g_[3]=f2bf(av_.w); g_[4]=(short)0x3f80; g_[5]=0; g_[6]=0; g_[7]=0;     \
        XA = g_;                                                               \
      } else XA = zero8;                                                       \
    }                                                                          \
  }

// HEAVY: h-dependent step work, at wave priority 1 (T5). PH literal.
// h(T-1) fp32 via hf32[PH] (own 4 units, lossless); bf16 hbuf -> MFMA frags.
// Weights pre-scaled: Cr,Cz = -L2E*preact; Cnh,cgn = 2*L2E*preact parts.
#define HEAVY(PH, T, IT)                                                       \
  {                                                                            \
    __builtin_amdgcn_s_setprio(1);                                             \
    short8 Ah0 = *(const short8*)((const char*)hbuf[PH] + rdaddr0);            \
    short8 Ah1 = *(const short8*)((const char*)hbuf[PH] + rdaddr1);            \
    f32x4 hp = *(const f32x4*)((const char*)hf32[PH] + f32addr);               \
    f32x4 Cr  = MFMA(AH[0][1], Ah1, MFMA(AH[0][0], Ah0, cgr));                 \
    f32x4 Cz  = MFMA(AH[1][1], Ah1, MFMA(AH[1][0], Ah0, cgz));                 \
    f32x4 Cnh = MFMA(AH[2][1], Ah1, MFMA(AH[2][0], Ah0, bhn4));                \
    f32x4 Crw = zf;                                                            \
    const bool dorw_ = (w == ((IT) & 3));                                      \
    if (dorw_) Crw = MFMA(AR[1], Ah1, MFMA(AR[0], Ah0, zf));                   \
    _Pragma("unroll")                                                          \
    for (int reg = 0; reg < 4; ++reg) {                                        \
      float rr   = frcp(1.0f + __builtin_amdgcn_exp2f(Cr[reg]));               \
      float zz   = frcp(1.0f + __builtin_amdgcn_exp2f(Cz[reg]));               \
      float E    = __builtin_amdgcn_exp2f(__builtin_fmaf(rr, Cnh[reg], cgn[reg])); \
      float nn   = __builtin_fmaf(-2.0f, frcp(E + 1.0f), 1.0f);                \
      hold[reg]  = __builtin_fmaf(zz, hp[reg] - nn, nn);                       \
    }                                                                          \
    unsigned pk0 = cvt_pk(hold[0], hold[1]);                                   \
    unsigned pk1 = cvt_pk(hold[2], hold[3]);                                   \
    *(uint2*)((char*)hbuf[PH ^ 1] + wraddr) = make_uint2(pk0, pk1);            \
    *(f32x4*)((char*)hf32[PH ^ 1] + f32addr) = hold;                           \
    if (dorw_ && q == 0 && (T) > 0)                                            \
      rew[(size_t)(bid * 16 + c) * TT + (T) - 1] = Crw[0] + brr;               \
    asm volatile("s_waitcnt lgkmcnt(0)" ::: "memory");                         \
    __builtin_amdgcn_s_setprio(0);                                             \
  }

// LIGHT: gi(T2) from the x ring, then refill ring with x(T2+2). No LDS ops.
#define LIGHT(T2)                                                              \
  {                                                                            \
    cgr = MFMA(AX[0][1], xa, MFMA(AX[0][0], xo, zf));                          \
    cgz = MFMA(AX[1][1], xa, MFMA(AX[1][0], xo, zf));                          \
    cgn = MFMA(AX[2][1], xa, MFMA(AX[2][0], xo, zf));                          \
    LOADX(xo, xa, (T2) + 2)                                                    \
  }

template<bool PACKED>
__global__ __launch_bounds__(512, 1)
void gru_fused(const unsigned short* __restrict__ xext,
               const float* __restrict__ obs, const float* __restrict__ act,
               const float* __restrict__ W_ih, const float* __restrict__ b_ih,
               const float* __restrict__ W_hh, const float* __restrict__ b_hh,
               const float* __restrict__ W_r, const float* __restrict__ b_r,
               float* __restrict__ out)
{
    const int tid = threadIdx.x;
    const int set = tid >> 8;                // 0: even steps, 1: odd steps
    const int w = (tid >> 6) & 3;            // wave-in-set
    const int l = tid & 63, c = l & 15, q = l >> 4;
    const int bid = blockIdx.x;
    const int u0 = 16 * w + 4 * q;           // first of this lane's 4 units

    __shared__ __align__(16) unsigned short hbuf[2][16 * 64];  // bf16 [seq][unit]
    __shared__ __align__(16) float          hf32[2][16 * 64];  // fp32 [seq][unit]

    // ---- weight A-fragments, PRE-SCALED for the gate exp2s ----
    //   m=0 (r), m=1 (z): rows * -L2E;  m=2 (n): rows * +2*L2E.
    short8 AX[3][2], AH[3][2];
#pragma unroll
    for (int m = 0; m < 3; ++m) {
        const float sc = (m == 2) ? (2.0f * L2E) : (-L2E);
        const int j = w + 4 * m;             // tile: w=r, w+4=z, w+8=n
        const int g = 16 * j + c;            // gate row (A-row = c)
        {   // x-weights, k 0..31
            const float* wp = W_ih + (size_t)g * 36 + 8 * q;
            float4 a = *(const float4*)wp, b = *(const float4*)(wp + 4);
            short8 f;
            f[0]=f2bf(a.x*sc); f[1]=f2bf(a.y*sc); f[2]=f2bf(a.z*sc); f[3]=f2bf(a.w*sc);
            f[4]=f2bf(b.x*sc); f[5]=f2bf(b.y*sc); f[6]=f2bf(b.z*sc); f[7]=f2bf(b.w*sc);
            AX[m][0] = f;
        }
        {   // x-weights, k 32..63 (act + bias slot + zeros)
            short8 f;
#pragma unroll
            for (int i = 0; i < 8; ++i) {
                int k = 32 + 8 * q + i;
                float v = 0.f;
                if (k < 36)       v = W_ih[(size_t)g * 36 + k];
                else if (k == 36) v = b_ih[g] + (g < 128 ? b_hh[g] : 0.f);
                f[i] = f2bf(v * sc);
            }
            AX[m][1] = f;
        }
#pragma unroll
        for (int kk = 0; kk < 2; ++kk) {     // h-weights
            const float* wp = W_hh + (size_t)g * HH + 32 * kk + 8 * q;
            float4 a = *(const float4*)wp, b = *(const float4*)(wp + 4);
            short8 f;
            f[0]=f2bf(a.x*sc); f[1]=f2bf(a.y*sc); f[2]=f2bf(a.z*sc); f[3]=f2bf(a.w*sc);
            f[4]=f2bf(b.x*sc); f[5]=f2bf(b.y*sc); f[6]=f2bf(b.z*sc); f[7]=f2bf(b.w*sc);
            AH[m][kk] = f;
        }
    }
    short8 AR[2];                            // reward tile: A-row 0 = W_r (unscaled)
#pragma unroll
    for (int kk = 0; kk < 2; ++kk) {
        short8 f;
#pragma unroll
        for (int i = 0; i < 8; ++i) {
            int k = 32 * kk + 8 * q + i;
            f[i] = (c == 0) ? (short)f2bf(W_r[k]) : (short)0;
        }
        AR[kk] = f;
    }

    f32x4 bhn4;                              // Cnh C-init: 2*L2E * b_hh[n-rows]
#pragma unroll
    for (int reg = 0; reg < 4; ++reg) bhn4[reg] = b_hh[128 + u0 + reg] * (2.0f * L2E);
    const float brr = b_r[0];

    // ---- LDS byte offsets ----
    // hbuf: XOR swizzle on 16B slots within 128B seq-rows (proven benign).
    const int swz = c & 7;
    const int wraddr  = c * 128 + ((((u0 >> 3)) ^ swz) << 4) + (u0 & 7) * 2;
    const int rdaddr0 = c * 128 + ((q ^ swz) << 4);          // units 8q..8q+7
    const int rdaddr1 = c * 128 + (((4 + q) ^ swz) << 4);    // units 32+8q..+7
    // hf32: 256B seq-rows of 16 float4-slots; lane's slot (4w+q), XOR-swizzled.
    const int f32addr = c * 256 + (((4 * w + q) ^ swz) << 4);

    // ---- x stream base pointers (lane's seq = c) ----
    const size_t row = (size_t)(bid * 16 + c) * TT;
    const unsigned short* px = xext + row * 40;
    const float* po = obs + row * DOBS;
    const float* pa = act + row * DACT;

    const short8 zero8 = {0, 0, 0, 0, 0, 0, 0, 0};
    const f32x4 zf = {0.f, 0.f, 0.f, 0.f};

    // ---- init: zero hbuf (4KB) + hf32 (8KB); prime per-set x/gi state ----
    ((uint2*)hbuf)[tid] = make_uint2(0u, 0u);          // 512 x 8B = 4KB
    ((f32x4*)hf32)[tid] = zf;                          // 512 x 16B = 8KB
    short8 xo, xa;
    f32x4 cgr = zf, cgz = zf, cgn = zf;
    if (set == 0) {
        LOADX(xo, xa, 0)                    // x(0)
        cgr = MFMA(AX[0][1], xa, MFMA(AX[0][0], xo, zf));   // gi(0)
        cgz = MFMA(AX[1][1], xa, MFMA(AX[1][0], xo, zf));
        cgn = MFMA(AX[2][1], xa, MFMA(AX[2][0], xo, zf));
        LOADX(xo, xa, 2)                    // x(2) -> ring
    } else {
        LOADX(xo, xa, 1)                    // x(1) -> ring (gi(1) built in light)
    }
    f32x4 hold = zf;
    asm volatile("s_waitcnt lgkmcnt(0)" ::: "memory");
    __builtin_amdgcn_s_barrier();
    asm volatile("" ::: "memory");

    float* rew = out + (size_t)BB * HH;      // out: [h_final B*H][rewards B*T]

#pragma unroll 1
    for (int it = 0; it < TT / 2; ++it) {
        const int Ta = 2 * it, Tb = 2 * it + 1;
        // half 1: A heavy (step Ta) @prio1, B light (gi for Tb) @prio0
        if (set == 0) { HEAVY(0, Ta, it) } else { LIGHT(Tb) }
        __builtin_amdgcn_s_barrier();
        asm volatile("" ::: "memory");
        // half 2: B heavy (step Tb) @prio1, A light (gi for Ta+2) @prio0
        if (set == 1) { HEAVY(1, Tb, it) } else { LIGHT(Ta + 2) }
        __builtin_amdgcn_s_barrier();
        asm volatile("" ::: "memory");
    }

    // ---- epilogue: h(T-1) is in hbuf[0]/hold of set B (T-1 = 1023 odd) ----
    if (set == 1) {
        if (w == 3) {
            short8 Ah0 = *(const short8*)((const char*)hbuf[0] + rdaddr0);
            short8 Ah1 = *(const short8*)((const char*)hbuf[0] + rdaddr1);
            f32x4 Crw = MFMA(AR[0], Ah0, zf);
            Crw = MFMA(AR[1], Ah1, Crw);
            if (q == 0)
                rew[(size_t)(bid * 16 + c) * TT + TT - 1] = Crw[0] + brr;
        }
        *(float4*)(out + (size_t)(bid * 16 + c) * HH + u0) =
            make_float4(hold[0], hold[1], hold[2], hold[3]);
    }
}

// ------------------------------------------------------------------- host ---
extern "C" void kernel_launch(void* const* d_in, const int* in_sizes, int n_in,
                              void* d_out, int out_size, void* d_ws, size_t ws_size,
                              hipStream_t stream)
{
    const float* obs    = (const float*)d_in[0];
    const float* action = (const float*)d_in[1];
    const float* W_ih   = (const float*)d_in[2];
    const float* b_ih   = (const float*)d_in[3];
    const float* W_hh   = (const float*)d_in[4];
    const float* b_hh   = (const float*)d_in[5];
    const float* W_r    = (const float*)d_in[6];
    const float* b_r    = (const float*)d_in[7];
    float* out          = (float*)d_out;

    // xext (80 MB) + slack rows so the unclamped t+4 prefetch stays in ws.
    const size_t xext_bytes = ((size_t)BB * TT + 8) * 40 * sizeof(unsigned short);
    if (ws_size >= xext_bytes) {
        unsigned short* xext = (unsigned short*)d_ws;
        pack_x<<<dim3((BB * TT) / 256), dim3(256), 0, stream>>>(obs, action, xext);
        gru_fused<true><<<dim3(BB / 16), dim3(512), 0, stream>>>(
            xext, obs, action, W_ih, b_ih, W_hh, b_hh, W_r, b_r, out);
    } else {
        gru_fused<false><<<dim3(BB / 16), dim3(512), 0, stream>>>(
            nullptr, obs, action, W_ih, b_ih, W_hh, b_hh, W_r, b_r, out);
    }
}